// Round 3
// baseline (1246.682 us; speedup 1.0000x reference)
//
#include <hip/hip_runtime.h>
#include <math.h>

// GCN 2-layer + sigmoid head via dst-bucketed edge binning + LDS aggregation.
//   bucket(d) = d >> 9  (NB=512 nodes/bucket, B=391 buckets for n=200000)
//   binned edge word: ((d & 511) << 18) | s   (s < 2^18; n <= 262144)
//   layer: agg[d] = sum_{s->d} g[s] (LDS atomics) + g[d] (self, epilogue)
//          out[d] = relu(dinv[d]*agg[d] + b) -> next-layer GEMM, fused.

#define TPB 256
#define NB_SHIFT 9
#define NB 512
#define MAXB 512
#define CHUNK 8192

__global__ void k_zero_i32(int* __restrict__ p, int n) {
    int i = blockIdx.x * blockDim.x + threadIdx.x;
    if (i < n) p[i] = 0;
}

// global per-bucket edge counts via per-block LDS histograms
__global__ void k_hist(const int* __restrict__ dst, int* __restrict__ bc, int e, int nb) {
    __shared__ int h[MAXB];
    for (int t = threadIdx.x; t < nb; t += blockDim.x) h[t] = 0;
    __syncthreads();
    int stride = gridDim.x * blockDim.x;
    for (int i = blockIdx.x * blockDim.x + threadIdx.x; i < e; i += stride)
        atomicAdd(&h[dst[i] >> NB_SHIFT], 1);
    __syncthreads();
    for (int t = threadIdx.x; t < nb; t += blockDim.x)
        if (h[t]) atomicAdd(&bc[t], h[t]);
}

// exclusive scan of bucket counts (nb <= 512), single block of 512
__global__ void k_scan(const int* __restrict__ bc, int* __restrict__ bbase,
                       int* __restrict__ gcur, int nb) {
    __shared__ int sm[MAXB];
    int t = threadIdx.x;
    int v = (t < nb) ? bc[t] : 0;
    sm[t] = v;
    __syncthreads();
    for (int off = 1; off < MAXB; off <<= 1) {
        int a = (t >= off) ? sm[t - off] : 0;
        __syncthreads();
        sm[t] += a;
        __syncthreads();
    }
    if (t < nb) { int ex = sm[t] - v; bbase[t] = ex; gcur[t] = ex; }
}

// bin edges into bucket regions; per-block grouped reservation for write locality
__global__ void k_fillbin(const int* __restrict__ src, const int* __restrict__ dst,
                          int* __restrict__ gcur, int* __restrict__ binned, int e, int nb) {
    __shared__ int h[MAXB];
    int c0 = blockIdx.x * CHUNK;
    int c1 = min(e, c0 + CHUNK);
    for (int t = threadIdx.x; t < nb; t += blockDim.x) h[t] = 0;
    __syncthreads();
    for (int i = c0 + threadIdx.x; i < c1; i += blockDim.x)
        atomicAdd(&h[dst[i] >> NB_SHIFT], 1);
    __syncthreads();
    for (int t = threadIdx.x; t < nb; t += blockDim.x) {
        int hv = h[t];
        h[t] = hv ? atomicAdd(&gcur[t], hv) : 0;
    }
    __syncthreads();
    for (int i = c0 + threadIdx.x; i < c1; i += blockDim.x) {
        int d = dst[i], s = src[i];
        int pos = atomicAdd(&h[d >> NB_SHIFT], 1);
        binned[pos] = ((d & (NB - 1)) << 18) | s;
    }
}

// per-bucket in-degree -> dinv = rsqrt(deg+1)
__global__ void k_dinvb(const int* __restrict__ binned, const int* __restrict__ bbase,
                        const int* __restrict__ bc, float* __restrict__ dinv, int n) {
    __shared__ int cnt[NB];
    int b = blockIdx.x;
    for (int t = threadIdx.x; t < NB; t += blockDim.x) cnt[t] = 0;
    __syncthreads();
    int base = bbase[b], c = bc[b];
    for (int j = base + threadIdx.x; j < base + c; j += blockDim.x)
        atomicAdd(&cnt[binned[j] >> 18], 1);
    __syncthreads();
    for (int t = threadIdx.x; t < NB; t += blockDim.x) {
        int i = (b << NB_SHIFT) + t;
        if (i < n) dinv[i] = rsqrtf((float)(cnt[t] + 1));
    }
}

// g1[i] = (x[i] @ W1) * dinv[i]
__global__ void k_g1(const float* __restrict__ x, const float* __restrict__ W1,
                     const float* __restrict__ dinv, float* __restrict__ g1, int n) {
    __shared__ float w[96];  // 6 x 16
    if (threadIdx.x < 96) w[threadIdx.x] = W1[threadIdx.x];
    __syncthreads();
    int i = blockIdx.x * blockDim.x + threadIdx.x;
    if (i >= n) return;
    float xv[6];
#pragma unroll
    for (int k = 0; k < 6; k++) xv[k] = x[i * 6 + k];
    float di = dinv[i];
    float4* out = (float4*)g1;
#pragma unroll
    for (int q = 0; q < 4; q++) {
        float4 o;
        float* op = (float*)&o;
#pragma unroll
        for (int r = 0; r < 4; r++) {
            int f = q * 4 + r;
            float h = 0.0f;
#pragma unroll
            for (int k = 0; k < 6; k++) h += xv[k] * w[k * 16 + f];
            op[r] = h * di;
        }
        out[i * 4 + q] = o;
    }
}

// layer-1 aggregation per bucket (LDS atomics, stride 17 to spread banks),
// fused epilogue: t = relu(dinv*(acc+self)+b1); g2 = (t @ W2) * dinv
__global__ void __launch_bounds__(TPB) k_agg1(
        const float* __restrict__ g1, const int* __restrict__ binned,
        const int* __restrict__ bbase, const int* __restrict__ bc,
        const float* __restrict__ dinv, const float* __restrict__ b1,
        const float* __restrict__ W2, float* __restrict__ g2, int n) {
    __shared__ float acc[NB * 17];
    __shared__ float w[128];  // 16 x 8
    __shared__ float bb[16];
    if (threadIdx.x < 128) w[threadIdx.x] = W2[threadIdx.x];
    if (threadIdx.x < 16) bb[threadIdx.x] = b1[threadIdx.x];
    for (int t = threadIdx.x; t < NB * 17; t += blockDim.x) acc[t] = 0.0f;
    __syncthreads();
    int b = blockIdx.x;
    int base = bbase[b], c = bc[b];
    const float4* gv = (const float4*)g1;
    for (int j = base + threadIdx.x; j < base + c; j += blockDim.x) {
        int p = binned[j];
        int s = p & 0x3FFFF, dl = p >> 18;
        float4 a0 = gv[s * 4 + 0], a1 = gv[s * 4 + 1], a2 = gv[s * 4 + 2], a3 = gv[s * 4 + 3];
        float* ap = &acc[dl * 17];
        atomicAdd(ap + 0, a0.x);  atomicAdd(ap + 1, a0.y);
        atomicAdd(ap + 2, a0.z);  atomicAdd(ap + 3, a0.w);
        atomicAdd(ap + 4, a1.x);  atomicAdd(ap + 5, a1.y);
        atomicAdd(ap + 6, a1.z);  atomicAdd(ap + 7, a1.w);
        atomicAdd(ap + 8, a2.x);  atomicAdd(ap + 9, a2.y);
        atomicAdd(ap + 10, a2.z); atomicAdd(ap + 11, a2.w);
        atomicAdd(ap + 12, a3.x); atomicAdd(ap + 13, a3.y);
        atomicAdd(ap + 14, a3.z); atomicAdd(ap + 15, a3.w);
    }
    __syncthreads();
    for (int node = threadIdx.x; node < NB; node += blockDim.x) {
        int i = (b << NB_SHIFT) + node;
        if (i >= n) continue;
        float di = dinv[i];
        float4 s0 = gv[i * 4 + 0], s1 = gv[i * 4 + 1], s2 = gv[i * 4 + 2], s3 = gv[i * 4 + 3];
        float self[16] = {s0.x, s0.y, s0.z, s0.w, s1.x, s1.y, s1.z, s1.w,
                          s2.x, s2.y, s2.z, s2.w, s3.x, s3.y, s3.z, s3.w};
        float tt[16];
#pragma unroll
        for (int f = 0; f < 16; f++)
            tt[f] = fmaxf(di * (acc[node * 17 + f] + self[f]) + bb[f], 0.0f);
        float2* g2v = (float2*)g2;
#pragma unroll
        for (int q = 0; q < 4; q++) {
            float2 o;
#pragma unroll
            for (int r = 0; r < 2; r++) {
                int f2 = q * 2 + r;
                float h = 0.0f;
#pragma unroll
                for (int f = 0; f < 16; f++) h += tt[f] * w[f * 8 + f2];
                ((float*)&o)[r] = h * di;
            }
            g2v[i * 4 + q] = o;
        }
    }
}

// layer-2 aggregation per bucket (stride 9), fused head: sigmoid((relu(...)@Wfc)+bfc)
__global__ void __launch_bounds__(TPB) k_agg2(
        const float* __restrict__ g2, const int* __restrict__ binned,
        const int* __restrict__ bbase, const int* __restrict__ bc,
        const float* __restrict__ dinv, const float* __restrict__ b2,
        const float* __restrict__ Wfc, const float* __restrict__ bfc,
        float* __restrict__ out, int n) {
    __shared__ float acc[NB * 9];
    __shared__ float w[8];
    __shared__ float bb[8];
    __shared__ float bf;
    if (threadIdx.x < 8) { w[threadIdx.x] = Wfc[threadIdx.x]; bb[threadIdx.x] = b2[threadIdx.x]; }
    if (threadIdx.x == 0) bf = bfc[0];
    for (int t = threadIdx.x; t < NB * 9; t += blockDim.x) acc[t] = 0.0f;
    __syncthreads();
    int b = blockIdx.x;
    int base = bbase[b], c = bc[b];
    const float4* gv = (const float4*)g2;
    for (int j = base + threadIdx.x; j < base + c; j += blockDim.x) {
        int p = binned[j];
        int s = p & 0x3FFFF, dl = p >> 18;
        float4 a0 = gv[s * 2 + 0], a1 = gv[s * 2 + 1];
        float* ap = &acc[dl * 9];
        atomicAdd(ap + 0, a0.x); atomicAdd(ap + 1, a0.y);
        atomicAdd(ap + 2, a0.z); atomicAdd(ap + 3, a0.w);
        atomicAdd(ap + 4, a1.x); atomicAdd(ap + 5, a1.y);
        atomicAdd(ap + 6, a1.z); atomicAdd(ap + 7, a1.w);
    }
    __syncthreads();
    for (int node = threadIdx.x; node < NB; node += blockDim.x) {
        int i = (b << NB_SHIFT) + node;
        if (i >= n) continue;
        float di = dinv[i];
        float4 s0 = gv[i * 2 + 0], s1 = gv[i * 2 + 1];
        float self[8] = {s0.x, s0.y, s0.z, s0.w, s1.x, s1.y, s1.z, s1.w};
        float o = bf;
#pragma unroll
        for (int f = 0; f < 8; f++) {
            float h = fmaxf(di * (acc[node * 9 + f] + self[f]) + bb[f], 0.0f);
            o += h * w[f];
        }
        out[i] = 1.0f / (1.0f + expf(-o));
    }
}

extern "C" void kernel_launch(void* const* d_in, const int* in_sizes, int n_in,
                              void* d_out, int out_size, void* d_ws, size_t ws_size,
                              hipStream_t stream) {
    const float* x   = (const float*)d_in[0];
    const int*   ei  = (const int*)d_in[1];
    const float* W1  = (const float*)d_in[2];
    const float* b1  = (const float*)d_in[3];
    const float* W2  = (const float*)d_in[4];
    const float* b2  = (const float*)d_in[5];
    const float* Wfc = (const float*)d_in[6];
    const float* bfc = (const float*)d_in[7];
    float* out = (float*)d_out;

    const int n = in_sizes[0] / 6;   // 200000 (must be <= 262144 for 18-bit packing)
    const int e = in_sizes[1] / 2;   // 6400000
    const int* src = ei;
    const int* dst = ei + e;
    const int nb = (n + NB - 1) >> NB_SHIFT;  // 391

    int* bc     = (int*)d_ws;            // MAXB
    int* bbase  = bc + MAXB;             // MAXB
    int* gcur   = bbase + MAXB;          // MAXB
    int* binned = gcur + MAXB;           // e
    float* dinv = (float*)(binned + e);  // n
    float* g1   = dinv + n;              // 16n
    float* g2   = g1 + 16 * (size_t)n;   // 8n

    int gn = (n + TPB - 1) / TPB;
    int nblk = (e + CHUNK - 1) / CHUNK;  // 782

    k_zero_i32<<<1, MAXB, 0, stream>>>(bc, MAXB);
    k_hist<<<512, TPB, 0, stream>>>(dst, bc, e, nb);
    k_scan<<<1, MAXB, 0, stream>>>(bc, bbase, gcur, nb);
    k_fillbin<<<nblk, TPB, 0, stream>>>(src, dst, gcur, binned, e, nb);
    k_dinvb<<<nb, TPB, 0, stream>>>(binned, bbase, bc, dinv, n);
    k_g1<<<gn, TPB, 0, stream>>>(x, W1, dinv, g1, n);
    k_agg1<<<nb, TPB, 0, stream>>>(g1, binned, bbase, bc, dinv, b1, W2, g2, n);
    k_agg2<<<nb, TPB, 0, stream>>>(g2, binned, bbase, bc, dinv, b2, Wfc, bfc, out, n);
}

// Round 4
// 1092.362 us; speedup vs baseline: 1.1413x; 1.1413x over previous
//
#include <hip/hip_runtime.h>
#include <math.h>

// GCN 2-layer + sigmoid head.
// Pipeline: bucket edges by dst (coarse, NB=256 nodes/bucket) ->
//   per-(bucket,split) LDS aggregation -> coalesced global fp32 atomic merge ->
//   per-node fused epilogues (norm, bias, relu, next GEMM / sigmoid head).
// binned word: ((d & 255) << 18) | s   (s < 2^18; n <= 262144)

#define TPB 256
#define NBS 8
#define NB 256          // nodes per bucket
#define MAXB 1024       // max buckets (n <= 262144 -> nb <= 1024)
#define CHUNK 8192      // edges per fillbin block
#define SPLIT 8         // blocks per bucket in aggregation

__global__ void k_zero_i32(int* __restrict__ p, int n) {
    int i = blockIdx.x * blockDim.x + threadIdx.x;
    if (i < n) p[i] = 0;
}

__global__ void k_zero_f4(float4* __restrict__ p, int n4) {
    int i = blockIdx.x * blockDim.x + threadIdx.x;
    if (i < n4) p[i] = make_float4(0.f, 0.f, 0.f, 0.f);
}

// global per-bucket edge counts via per-block LDS histograms
__global__ void k_hist(const int* __restrict__ dst, int* __restrict__ bc, int e, int nb) {
    __shared__ int h[MAXB];
    for (int t = threadIdx.x; t < nb; t += blockDim.x) h[t] = 0;
    __syncthreads();
    int stride = gridDim.x * blockDim.x;
    for (int i = blockIdx.x * blockDim.x + threadIdx.x; i < e; i += stride)
        atomicAdd(&h[dst[i] >> NBS], 1);
    __syncthreads();
    for (int t = threadIdx.x; t < nb; t += blockDim.x)
        if (h[t]) atomicAdd(&bc[t], h[t]);
}

// exclusive scan of bucket counts (nb <= 1024), single block of 1024
__global__ void k_scan(const int* __restrict__ bc, int* __restrict__ bbase,
                       int* __restrict__ gcur, int nb) {
    __shared__ int sm[MAXB];
    int t = threadIdx.x;
    int v = (t < nb) ? bc[t] : 0;
    sm[t] = v;
    __syncthreads();
    for (int off = 1; off < MAXB; off <<= 1) {
        int a = (t >= off) ? sm[t - off] : 0;
        __syncthreads();
        sm[t] += a;
        __syncthreads();
    }
    if (t < nb) { int ex = sm[t] - v; bbase[t] = ex; gcur[t] = ex; }
}

// bin edges into bucket regions; per-block grouped reservation for write locality
__global__ void k_fillbin(const int* __restrict__ src, const int* __restrict__ dst,
                          int* __restrict__ gcur, int* __restrict__ binned, int e, int nb) {
    __shared__ int h[MAXB];
    int c0 = blockIdx.x * CHUNK;
    int c1 = min(e, c0 + CHUNK);
    for (int t = threadIdx.x; t < nb; t += blockDim.x) h[t] = 0;
    __syncthreads();
    for (int i = c0 + threadIdx.x; i < c1; i += blockDim.x)
        atomicAdd(&h[dst[i] >> NBS], 1);
    __syncthreads();
    for (int t = threadIdx.x; t < nb; t += blockDim.x) {
        int hv = h[t];
        h[t] = hv ? atomicAdd(&gcur[t], hv) : 0;
    }
    __syncthreads();
    for (int i = c0 + threadIdx.x; i < c1; i += blockDim.x) {
        int d = dst[i], s = src[i];
        int pos = atomicAdd(&h[d >> NBS], 1);
        binned[pos] = ((d & (NB - 1)) << 18) | s;
    }
}

// per-bucket in-degree -> dinv = rsqrt(deg+1)
__global__ void k_dinvb(const int* __restrict__ binned, const int* __restrict__ bbase,
                        const int* __restrict__ bc, float* __restrict__ dinv, int n) {
    __shared__ int cnt[NB];
    int b = blockIdx.x;
    if (threadIdx.x < NB) cnt[threadIdx.x] = 0;
    __syncthreads();
    int base = bbase[b], c = bc[b];
    for (int j = base + threadIdx.x; j < base + c; j += blockDim.x)
        atomicAdd(&cnt[binned[j] >> 18], 1);
    __syncthreads();
    if (threadIdx.x < NB) {
        int i = (b << NBS) + threadIdx.x;
        if (i < n) dinv[i] = rsqrtf((float)(cnt[threadIdx.x] + 1));
    }
}

// g1[i] = (x[i] @ W1) * dinv[i]
__global__ void k_g1(const float* __restrict__ x, const float* __restrict__ W1,
                     const float* __restrict__ dinv, float* __restrict__ g1, int n) {
    __shared__ float w[96];  // 6 x 16
    if (threadIdx.x < 96) w[threadIdx.x] = W1[threadIdx.x];
    __syncthreads();
    int i = blockIdx.x * blockDim.x + threadIdx.x;
    if (i >= n) return;
    float xv[6];
#pragma unroll
    for (int k = 0; k < 6; k++) xv[k] = x[i * 6 + k];
    float di = dinv[i];
    float4* out = (float4*)g1;
#pragma unroll
    for (int q = 0; q < 4; q++) {
        float4 o;
        float* op = (float*)&o;
#pragma unroll
        for (int r = 0; r < 4; r++) {
            int f = q * 4 + r;
            float h = 0.0f;
#pragma unroll
            for (int k = 0; k < 6; k++) h += xv[k] * w[k * 16 + f];
            op[r] = h * di;
        }
        out[i * 4 + q] = o;
    }
}

// split-bucket aggregation, F=16: LDS acc (stride 17), coalesced atomic merge
__global__ void __launch_bounds__(TPB) k_agg1(
        const float* __restrict__ g1, const int* __restrict__ binned,
        const int* __restrict__ bbase, const int* __restrict__ bc,
        float* __restrict__ agg) {
    __shared__ float acc[NB * 17];
    for (int t = threadIdx.x; t < NB * 17; t += TPB) acc[t] = 0.0f;
    __syncthreads();
    int b = blockIdx.x / SPLIT, sp = blockIdx.x % SPLIT;
    int base = bbase[b], c = bc[b];
    int lo = base + (int)(((long long)c * sp) / SPLIT);
    int hi = base + (int)(((long long)c * (sp + 1)) / SPLIT);
    const float4* gv = (const float4*)g1;
    int j = lo + threadIdx.x;
    while (j + TPB < hi) {
        int p0 = binned[j], p1 = binned[j + TPB];
        int s0 = p0 & 0x3FFFF, d0 = p0 >> 18;
        int s1 = p1 & 0x3FFFF, d1 = p1 >> 18;
        float4 a0 = gv[s0 * 4 + 0], a1 = gv[s0 * 4 + 1], a2 = gv[s0 * 4 + 2], a3 = gv[s0 * 4 + 3];
        float4 c0 = gv[s1 * 4 + 0], c1 = gv[s1 * 4 + 1], c2 = gv[s1 * 4 + 2], c3 = gv[s1 * 4 + 3];
        float* ap = &acc[d0 * 17];
        atomicAdd(ap + 0, a0.x);  atomicAdd(ap + 1, a0.y);
        atomicAdd(ap + 2, a0.z);  atomicAdd(ap + 3, a0.w);
        atomicAdd(ap + 4, a1.x);  atomicAdd(ap + 5, a1.y);
        atomicAdd(ap + 6, a1.z);  atomicAdd(ap + 7, a1.w);
        atomicAdd(ap + 8, a2.x);  atomicAdd(ap + 9, a2.y);
        atomicAdd(ap + 10, a2.z); atomicAdd(ap + 11, a2.w);
        atomicAdd(ap + 12, a3.x); atomicAdd(ap + 13, a3.y);
        atomicAdd(ap + 14, a3.z); atomicAdd(ap + 15, a3.w);
        float* bp = &acc[d1 * 17];
        atomicAdd(bp + 0, c0.x);  atomicAdd(bp + 1, c0.y);
        atomicAdd(bp + 2, c0.z);  atomicAdd(bp + 3, c0.w);
        atomicAdd(bp + 4, c1.x);  atomicAdd(bp + 5, c1.y);
        atomicAdd(bp + 6, c1.z);  atomicAdd(bp + 7, c1.w);
        atomicAdd(bp + 8, c2.x);  atomicAdd(bp + 9, c2.y);
        atomicAdd(bp + 10, c2.z); atomicAdd(bp + 11, c2.w);
        atomicAdd(bp + 12, c3.x); atomicAdd(bp + 13, c3.y);
        atomicAdd(bp + 14, c3.z); atomicAdd(bp + 15, c3.w);
        j += 2 * TPB;
    }
    if (j < hi) {
        int p0 = binned[j];
        int s0 = p0 & 0x3FFFF, d0 = p0 >> 18;
        float4 a0 = gv[s0 * 4 + 0], a1 = gv[s0 * 4 + 1], a2 = gv[s0 * 4 + 2], a3 = gv[s0 * 4 + 3];
        float* ap = &acc[d0 * 17];
        atomicAdd(ap + 0, a0.x);  atomicAdd(ap + 1, a0.y);
        atomicAdd(ap + 2, a0.z);  atomicAdd(ap + 3, a0.w);
        atomicAdd(ap + 4, a1.x);  atomicAdd(ap + 5, a1.y);
        atomicAdd(ap + 6, a1.z);  atomicAdd(ap + 7, a1.w);
        atomicAdd(ap + 8, a2.x);  atomicAdd(ap + 9, a2.y);
        atomicAdd(ap + 10, a2.z); atomicAdd(ap + 11, a2.w);
        atomicAdd(ap + 12, a3.x); atomicAdd(ap + 13, a3.y);
        atomicAdd(ap + 14, a3.z); atomicAdd(ap + 15, a3.w);
    }
    __syncthreads();
    float* dstp = agg + ((size_t)(b << NBS)) * 16;
    for (int idx = threadIdx.x; idx < NB * 16; idx += TPB) {
        float v = acc[(idx >> 4) * 17 + (idx & 15)];
        if (v != 0.0f) atomicAdd(&dstp[idx], v);
    }
}

// split-bucket aggregation, F=8 (stride 9)
__global__ void __launch_bounds__(TPB) k_agg2(
        const float* __restrict__ g2, const int* __restrict__ binned,
        const int* __restrict__ bbase, const int* __restrict__ bc,
        float* __restrict__ agg) {
    __shared__ float acc[NB * 9];
    for (int t = threadIdx.x; t < NB * 9; t += TPB) acc[t] = 0.0f;
    __syncthreads();
    int b = blockIdx.x / SPLIT, sp = blockIdx.x % SPLIT;
    int base = bbase[b], c = bc[b];
    int lo = base + (int)(((long long)c * sp) / SPLIT);
    int hi = base + (int)(((long long)c * (sp + 1)) / SPLIT);
    const float4* gv = (const float4*)g2;
    int j = lo + threadIdx.x;
    while (j + TPB < hi) {
        int p0 = binned[j], p1 = binned[j + TPB];
        int s0 = p0 & 0x3FFFF, d0 = p0 >> 18;
        int s1 = p1 & 0x3FFFF, d1 = p1 >> 18;
        float4 a0 = gv[s0 * 2 + 0], a1 = gv[s0 * 2 + 1];
        float4 c0 = gv[s1 * 2 + 0], c1 = gv[s1 * 2 + 1];
        float* ap = &acc[d0 * 9];
        atomicAdd(ap + 0, a0.x); atomicAdd(ap + 1, a0.y);
        atomicAdd(ap + 2, a0.z); atomicAdd(ap + 3, a0.w);
        atomicAdd(ap + 4, a1.x); atomicAdd(ap + 5, a1.y);
        atomicAdd(ap + 6, a1.z); atomicAdd(ap + 7, a1.w);
        float* bp = &acc[d1 * 9];
        atomicAdd(bp + 0, c0.x); atomicAdd(bp + 1, c0.y);
        atomicAdd(bp + 2, c0.z); atomicAdd(bp + 3, c0.w);
        atomicAdd(bp + 4, c1.x); atomicAdd(bp + 5, c1.y);
        atomicAdd(bp + 6, c1.z); atomicAdd(bp + 7, c1.w);
        j += 2 * TPB;
    }
    if (j < hi) {
        int p0 = binned[j];
        int s0 = p0 & 0x3FFFF, d0 = p0 >> 18;
        float4 a0 = gv[s0 * 2 + 0], a1 = gv[s0 * 2 + 1];
        float* ap = &acc[d0 * 9];
        atomicAdd(ap + 0, a0.x); atomicAdd(ap + 1, a0.y);
        atomicAdd(ap + 2, a0.z); atomicAdd(ap + 3, a0.w);
        atomicAdd(ap + 4, a1.x); atomicAdd(ap + 5, a1.y);
        atomicAdd(ap + 6, a1.z); atomicAdd(ap + 7, a1.w);
    }
    __syncthreads();
    float* dstp = agg + ((size_t)(b << NBS)) * 8;
    for (int idx = threadIdx.x; idx < NB * 8; idx += TPB) {
        float v = acc[(idx >> 3) * 9 + (idx & 7)];
        if (v != 0.0f) atomicAdd(&dstp[idx], v);
    }
}

// epilogue 1: t = relu(dinv*(agg1+g1)+b1); g2 = (t @ W2) * dinv
__global__ void k_post1(const float* __restrict__ agg1, const float* __restrict__ g1,
                        const float* __restrict__ dinv, const float* __restrict__ b1,
                        const float* __restrict__ W2, float* __restrict__ g2, int n) {
    __shared__ float w[128];  // 16 x 8
    __shared__ float bb[16];
    if (threadIdx.x < 128) w[threadIdx.x] = W2[threadIdx.x];
    if (threadIdx.x < 16) bb[threadIdx.x] = b1[threadIdx.x];
    __syncthreads();
    int i = blockIdx.x * blockDim.x + threadIdx.x;
    if (i >= n) return;
    const float4* av = (const float4*)agg1;
    const float4* gv = (const float4*)g1;
    float di = dinv[i];
    float tt[16];
#pragma unroll
    for (int q = 0; q < 4; q++) {
        float4 a = av[i * 4 + q];
        float4 g = gv[i * 4 + q];
        tt[q * 4 + 0] = fmaxf(di * (a.x + g.x) + bb[q * 4 + 0], 0.0f);
        tt[q * 4 + 1] = fmaxf(di * (a.y + g.y) + bb[q * 4 + 1], 0.0f);
        tt[q * 4 + 2] = fmaxf(di * (a.z + g.z) + bb[q * 4 + 2], 0.0f);
        tt[q * 4 + 3] = fmaxf(di * (a.w + g.w) + bb[q * 4 + 3], 0.0f);
    }
    float4* g2v = (float4*)g2;
#pragma unroll
    for (int q = 0; q < 2; q++) {
        float4 o;
#pragma unroll
        for (int r = 0; r < 4; r++) {
            int f2 = q * 4 + r;
            float h = 0.0f;
#pragma unroll
            for (int f = 0; f < 16; f++) h += tt[f] * w[f * 8 + f2];
            ((float*)&o)[r] = h * di;
        }
        g2v[i * 2 + q] = o;
    }
}

// epilogue 2: h = relu(dinv*(agg2+g2)+b2); out = sigmoid(h @ Wfc + bfc)
__global__ void k_post2(const float* __restrict__ agg2, const float* __restrict__ g2,
                        const float* __restrict__ dinv, const float* __restrict__ b2,
                        const float* __restrict__ Wfc, const float* __restrict__ bfc,
                        float* __restrict__ out, int n) {
    __shared__ float w[8];
    __shared__ float bb[8];
    __shared__ float bf;
    if (threadIdx.x < 8) { w[threadIdx.x] = Wfc[threadIdx.x]; bb[threadIdx.x] = b2[threadIdx.x]; }
    if (threadIdx.x == 0) bf = bfc[0];
    __syncthreads();
    int i = blockIdx.x * blockDim.x + threadIdx.x;
    if (i >= n) return;
    const float4* av = (const float4*)agg2;
    const float4* gv = (const float4*)g2;
    float di = dinv[i];
    float o = bf;
#pragma unroll
    for (int q = 0; q < 2; q++) {
        float4 a = av[i * 2 + q];
        float4 g = gv[i * 2 + q];
        o += fmaxf(di * (a.x + g.x) + bb[q * 4 + 0], 0.0f) * w[q * 4 + 0];
        o += fmaxf(di * (a.y + g.y) + bb[q * 4 + 1], 0.0f) * w[q * 4 + 1];
        o += fmaxf(di * (a.z + g.z) + bb[q * 4 + 2], 0.0f) * w[q * 4 + 2];
        o += fmaxf(di * (a.w + g.w) + bb[q * 4 + 3], 0.0f) * w[q * 4 + 3];
    }
    out[i] = 1.0f / (1.0f + expf(-o));
}

extern "C" void kernel_launch(void* const* d_in, const int* in_sizes, int n_in,
                              void* d_out, int out_size, void* d_ws, size_t ws_size,
                              hipStream_t stream) {
    const float* x   = (const float*)d_in[0];
    const int*   ei  = (const int*)d_in[1];
    const float* W1  = (const float*)d_in[2];
    const float* b1  = (const float*)d_in[3];
    const float* W2  = (const float*)d_in[4];
    const float* b2  = (const float*)d_in[5];
    const float* Wfc = (const float*)d_in[6];
    const float* bfc = (const float*)d_in[7];
    float* out = (float*)d_out;

    const int n = in_sizes[0] / 6;   // 200000 (<= 262144 for 18-bit packing)
    const int e = in_sizes[1] / 2;   // 6400000
    const int* src = ei;
    const int* dst = ei + e;
    const int nb = (n + NB - 1) >> NBS;   // 782
    const size_t np = (size_t)nb << NBS;  // padded node count (200192)

    int* bc     = (int*)d_ws;            // MAXB
    int* bbase  = bc + MAXB;             // MAXB
    int* gcur   = bbase + MAXB;          // MAXB
    int* binned = gcur + MAXB;           // e
    float* dinv = (float*)(binned + e);  // np
    float* g1   = dinv + np;             // 16 np
    float* g2   = g1 + 16 * np;          // 8 np
    float* agg1 = g2 + 8 * np;           // 16 np  (agg1+agg2 contiguous for one zero pass)
    float* agg2 = agg1 + 16 * np;        // 8 np

    int gn = (n + TPB - 1) / TPB;
    int nblk = (e + CHUNK - 1) / CHUNK;      // 782
    int z4 = (int)(np * 24 / 4);             // float4s to zero (agg1+agg2)

    k_zero_i32<<<1, MAXB, 0, stream>>>(bc, MAXB);
    k_hist<<<512, TPB, 0, stream>>>(dst, bc, e, nb);
    k_scan<<<1, MAXB, 0, stream>>>(bc, bbase, gcur, nb);
    k_fillbin<<<nblk, TPB, 0, stream>>>(src, dst, gcur, binned, e, nb);
    k_dinvb<<<nb, TPB, 0, stream>>>(binned, bbase, bc, dinv, n);
    k_zero_f4<<<(z4 + TPB - 1) / TPB, TPB, 0, stream>>>((float4*)agg1, z4);
    k_g1<<<gn, TPB, 0, stream>>>(x, W1, dinv, g1, n);
    k_agg1<<<nb * SPLIT, TPB, 0, stream>>>(g1, binned, bbase, bc, agg1);
    k_post1<<<gn, TPB, 0, stream>>>(agg1, g1, dinv, b1, W2, g2, n);
    k_agg2<<<nb * SPLIT, TPB, 0, stream>>>(g2, binned, bbase, bc, agg2);
    k_post2<<<gn, TPB, 0, stream>>>(agg2, g2, dinv, b2, Wfc, bfc, out, n);
}

// Round 5
// 528.504 us; speedup vs baseline: 2.3589x; 2.0669x over previous
//
#include <hip/hip_runtime.h>
#include <math.h>

// GCN 2-layer + sigmoid head. CSR pull-gather, zero fp32 atomics.
// Stage 1: bucket edges by dst (NB=256 nodes/bucket) -> binned[] (grouped writes)
// Stage 2: per-bucket LDS counting sort -> csr[] sorted by dst, rowptr[], dinv[]
// Stage 3: wave-per-node gather (4 lanes/edge, line-coalesced), register acc,
//          shfl butterfly reduce, fused epilogue (norm+bias+relu+next GEMV).

#define TPB 256
#define NBS 8
#define NB 256          // nodes per bucket
#define MAXB 1024       // max buckets (n <= 262144)
#define CHUNK 8192      // edges per fillbin block

__global__ void k_zero_i32(int* __restrict__ p, int n) {
    int i = blockIdx.x * blockDim.x + threadIdx.x;
    if (i < n) p[i] = 0;
}

// global per-bucket edge counts via per-block LDS histograms
__global__ void k_hist(const int* __restrict__ dst, int* __restrict__ bc, int e, int nb) {
    __shared__ int h[MAXB];
    for (int t = threadIdx.x; t < nb; t += blockDim.x) h[t] = 0;
    __syncthreads();
    int stride = gridDim.x * blockDim.x;
    for (int i = blockIdx.x * blockDim.x + threadIdx.x; i < e; i += stride)
        atomicAdd(&h[dst[i] >> NBS], 1);
    __syncthreads();
    for (int t = threadIdx.x; t < nb; t += blockDim.x)
        if (h[t]) atomicAdd(&bc[t], h[t]);
}

// exclusive scan of bucket counts (nb <= 1024), single block of 1024
__global__ void k_scan(const int* __restrict__ bc, int* __restrict__ bbase,
                       int* __restrict__ gcur, int nb) {
    __shared__ int sm[MAXB];
    int t = threadIdx.x;
    int v = (t < nb) ? bc[t] : 0;
    sm[t] = v;
    __syncthreads();
    for (int off = 1; off < MAXB; off <<= 1) {
        int a = (t >= off) ? sm[t - off] : 0;
        __syncthreads();
        sm[t] += a;
        __syncthreads();
    }
    if (t < nb) { int ex = sm[t] - v; bbase[t] = ex; gcur[t] = ex; }
}

// bin edges into bucket regions; per-block grouped reservation for write locality
// word: ((d & 255) << 18) | s
__global__ void k_fillbin(const int* __restrict__ src, const int* __restrict__ dst,
                          int* __restrict__ gcur, int* __restrict__ binned, int e, int nb) {
    __shared__ int h[MAXB];
    int c0 = blockIdx.x * CHUNK;
    int c1 = min(e, c0 + CHUNK);
    for (int t = threadIdx.x; t < nb; t += blockDim.x) h[t] = 0;
    __syncthreads();
    for (int i = c0 + threadIdx.x; i < c1; i += blockDim.x)
        atomicAdd(&h[dst[i] >> NBS], 1);
    __syncthreads();
    for (int t = threadIdx.x; t < nb; t += blockDim.x) {
        int hv = h[t];
        h[t] = hv ? atomicAdd(&gcur[t], hv) : 0;
    }
    __syncthreads();
    for (int i = c0 + threadIdx.x; i < c1; i += blockDim.x) {
        int d = dst[i], s = src[i];
        int pos = atomicAdd(&h[d >> NBS], 1);
        binned[pos] = ((d & (NB - 1)) << 18) | s;
    }
}

// per-bucket counting sort by d_local -> csr (src ids sorted by dst), rowptr, dinv
__global__ void __launch_bounds__(NB) k_sort(
        const int* __restrict__ binned, const int* __restrict__ bbase,
        const int* __restrict__ bc, int* __restrict__ csr, int* __restrict__ rowptr,
        float* __restrict__ dinv, int n, int nb, int e) {
    __shared__ int cnt[NB];
    __shared__ int excl[NB];
    __shared__ int curs[NB];
    int b = blockIdx.x, t = threadIdx.x;
    cnt[t] = 0;
    __syncthreads();
    int base = bbase[b], c = bc[b];
    for (int j = base + t; j < base + c; j += NB)
        atomicAdd(&cnt[binned[j] >> 18], 1);
    __syncthreads();
    int v = cnt[t];
    excl[t] = v;
    __syncthreads();
    for (int off = 1; off < NB; off <<= 1) {
        int a = (t >= off) ? excl[t - off] : 0;
        __syncthreads();
        excl[t] += a;
        __syncthreads();
    }
    int ex = excl[t] - v;  // exclusive prefix within bucket
    curs[t] = ex;
    int i = (b << NBS) + t;
    rowptr[i] = base + ex;
    if (i < n) dinv[i] = rsqrtf((float)(v + 1));
    if (b == nb - 1 && t == 0) rowptr[nb << NBS] = e;
    __syncthreads();
    for (int j = base + t; j < base + c; j += NB) {
        int p = binned[j];
        int pos = base + atomicAdd(&curs[p >> 18], 1);
        csr[pos] = p & 0x3FFFF;
    }
}

// g1[i] = (x[i] @ W1) * dinv[i]
__global__ void k_g1(const float* __restrict__ x, const float* __restrict__ W1,
                     const float* __restrict__ dinv, float* __restrict__ g1, int n) {
    __shared__ float w[96];  // 6 x 16
    if (threadIdx.x < 96) w[threadIdx.x] = W1[threadIdx.x];
    __syncthreads();
    int i = blockIdx.x * blockDim.x + threadIdx.x;
    if (i >= n) return;
    float xv[6];
#pragma unroll
    for (int k = 0; k < 6; k++) xv[k] = x[i * 6 + k];
    float di = dinv[i];
    float4* out = (float4*)g1;
#pragma unroll
    for (int q = 0; q < 4; q++) {
        float4 o;
        float* op = (float*)&o;
#pragma unroll
        for (int r = 0; r < 4; r++) {
            int f = q * 4 + r;
            float h = 0.0f;
#pragma unroll
            for (int k = 0; k < 6; k++) h += xv[k] * w[k * 16 + f];
            op[r] = h * di;
        }
        out[i * 4 + q] = o;
    }
}

// layer-1 gather: wave per node, 4 lanes/edge (quad=neighbor slot, fq=feature quad)
// fused epilogue: t = relu(dinv*(acc+self)+b1); g2 = (t @ W2) * dinv
__global__ void __launch_bounds__(TPB) k_gat1(
        const float* __restrict__ g1, const int* __restrict__ csr,
        const int* __restrict__ rowptr, const float* __restrict__ dinv,
        const float* __restrict__ b1, const float* __restrict__ W2,
        float* __restrict__ g2, int n) {
    __shared__ float w[128];   // 16 x 8
    __shared__ float bb[16];
    __shared__ float tsh[4][16];
    if (threadIdx.x < 128) w[threadIdx.x] = W2[threadIdx.x];
    if (threadIdx.x < 16) bb[threadIdx.x] = b1[threadIdx.x];
    __syncthreads();
    int wv = threadIdx.x >> 6;
    int lane = threadIdx.x & 63;
    int quad = lane >> 2, fq = lane & 3;
    int i = blockIdx.x * 4 + wv;
    bool valid = (i < n);
    int r0 = 0, r1 = 0;
    if (valid) { r0 = rowptr[i]; r1 = rowptr[i + 1]; }
    const float4* gv = (const float4*)g1;
    float4 a0 = make_float4(0.f, 0.f, 0.f, 0.f);
    float4 a1 = make_float4(0.f, 0.f, 0.f, 0.f);
    int j = r0 + quad;
    while (j + 16 < r1) {  // per-lane bound: each lane covers its slots exactly once
        int s0 = csr[j], s1 = csr[j + 16];
        float4 x0 = gv[s0 * 4 + fq];
        float4 x1 = gv[s1 * 4 + fq];
        a0.x += x0.x; a0.y += x0.y; a0.z += x0.z; a0.w += x0.w;
        a1.x += x1.x; a1.y += x1.y; a1.z += x1.z; a1.w += x1.w;
        j += 32;
    }
    if (j < r1) {
        int s0 = csr[j];
        float4 x0 = gv[s0 * 4 + fq];
        a0.x += x0.x; a0.y += x0.y; a0.z += x0.z; a0.w += x0.w;
    }
    float4 acc = make_float4(a0.x + a1.x, a0.y + a1.y, a0.z + a1.z, a0.w + a1.w);
#pragma unroll
    for (int m = 4; m <= 32; m <<= 1) {  // reduce across 16 neighbor-slot lanes
        acc.x += __shfl_xor(acc.x, m);
        acc.y += __shfl_xor(acc.y, m);
        acc.z += __shfl_xor(acc.z, m);
        acc.w += __shfl_xor(acc.w, m);
    }
    if (valid && quad == 0) {
        float di = dinv[i];
        float4 s = gv[i * 4 + fq];  // self-loop term
        float4 tq;
        tq.x = fmaxf(di * (acc.x + s.x) + bb[fq * 4 + 0], 0.0f);
        tq.y = fmaxf(di * (acc.y + s.y) + bb[fq * 4 + 1], 0.0f);
        tq.z = fmaxf(di * (acc.z + s.z) + bb[fq * 4 + 2], 0.0f);
        tq.w = fmaxf(di * (acc.w + s.w) + bb[fq * 4 + 3], 0.0f);
        ((float4*)tsh[wv])[fq] = tq;
    }
    __syncthreads();
    if (valid && quad == 0) {
        float di = dinv[i];
        float h0 = 0.0f, h1 = 0.0f;
#pragma unroll
        for (int f = 0; f < 16; f++) {
            float tv = tsh[wv][f];
            h0 += tv * w[f * 8 + fq * 2 + 0];
            h1 += tv * w[f * 8 + fq * 2 + 1];
        }
        ((float2*)g2)[i * 4 + fq] = make_float2(h0 * di, h1 * di);
    }
}

// layer-2 gather: wave per node, 2 lanes/edge (half=slot, fh=feature half)
// fused head: h = relu(dinv*(acc+self)+b2); out = sigmoid(h @ Wfc + bfc)
__global__ void __launch_bounds__(TPB) k_gat2(
        const float* __restrict__ g2, const int* __restrict__ csr,
        const int* __restrict__ rowptr, const float* __restrict__ dinv,
        const float* __restrict__ b2, const float* __restrict__ Wfc,
        const float* __restrict__ bfc, float* __restrict__ out, int n) {
    __shared__ float w[8];
    __shared__ float bb[8];
    __shared__ float bf;
    if (threadIdx.x < 8) { w[threadIdx.x] = Wfc[threadIdx.x]; bb[threadIdx.x] = b2[threadIdx.x]; }
    if (threadIdx.x == 0) bf = bfc[0];
    __syncthreads();
    int wv = threadIdx.x >> 6;
    int lane = threadIdx.x & 63;
    int half = lane >> 1, fh = lane & 1;
    int i = blockIdx.x * 4 + wv;
    bool valid = (i < n);
    int r0 = 0, r1 = 0;
    if (valid) { r0 = rowptr[i]; r1 = rowptr[i + 1]; }
    const float4* gv = (const float4*)g2;
    float4 acc = make_float4(0.f, 0.f, 0.f, 0.f);
    for (int j = r0 + half; j < r1; j += 32) {
        int s0 = csr[j];
        float4 x0 = gv[s0 * 2 + fh];
        acc.x += x0.x; acc.y += x0.y; acc.z += x0.z; acc.w += x0.w;
    }
#pragma unroll
    for (int m = 2; m <= 32; m <<= 1) {  // reduce across 32 neighbor-slot lanes
        acc.x += __shfl_xor(acc.x, m);
        acc.y += __shfl_xor(acc.y, m);
        acc.z += __shfl_xor(acc.z, m);
        acc.w += __shfl_xor(acc.w, m);
    }
    if (valid && half == 0) {  // lanes 0,1 both active -> shfl_xor(…,1) safe
        float di = dinv[i];
        float4 s = gv[i * 2 + fh];
        float o4 = 0.0f;
        o4 += fmaxf(di * (acc.x + s.x) + bb[fh * 4 + 0], 0.0f) * w[fh * 4 + 0];
        o4 += fmaxf(di * (acc.y + s.y) + bb[fh * 4 + 1], 0.0f) * w[fh * 4 + 1];
        o4 += fmaxf(di * (acc.z + s.z) + bb[fh * 4 + 2], 0.0f) * w[fh * 4 + 2];
        o4 += fmaxf(di * (acc.w + s.w) + bb[fh * 4 + 3], 0.0f) * w[fh * 4 + 3];
        float oo = o4 + __shfl_xor(o4, 1);
        if (fh == 0) out[i] = 1.0f / (1.0f + expf(-(oo + bf)));
    }
}

extern "C" void kernel_launch(void* const* d_in, const int* in_sizes, int n_in,
                              void* d_out, int out_size, void* d_ws, size_t ws_size,
                              hipStream_t stream) {
    const float* x   = (const float*)d_in[0];
    const int*   ei  = (const int*)d_in[1];
    const float* W1  = (const float*)d_in[2];
    const float* b1  = (const float*)d_in[3];
    const float* W2  = (const float*)d_in[4];
    const float* b2  = (const float*)d_in[5];
    const float* Wfc = (const float*)d_in[6];
    const float* bfc = (const float*)d_in[7];
    float* out = (float*)d_out;

    const int n = in_sizes[0] / 6;   // 200000 (<= 262144 for 18-bit packing)
    const int e = in_sizes[1] / 2;   // 6400000
    const int* src = ei;
    const int* dst = ei + e;
    const int nb = (n + NB - 1) >> NBS;   // 782
    const size_t np = (size_t)nb << NBS;  // padded node count (200192)

    int* bc     = (int*)d_ws;            // MAXB
    int* bbase  = bc + MAXB;             // MAXB
    int* gcur   = bbase + MAXB;          // MAXB
    int* binned = gcur + MAXB;           // e
    int* csr    = binned + e;            // e
    int* rowptr = csr + e;               // np + 4
    float* dinv = (float*)(rowptr + np + 4);  // np
    float* g1   = dinv + np;             // 16 np
    float* g2   = g1 + 16 * np;          // 8 np

    int gn = (n + TPB - 1) / TPB;
    int nblk = (e + CHUNK - 1) / CHUNK;  // 782
    int gw = (n + 3) / 4;                // wave-per-node blocks (4 waves/block)

    k_zero_i32<<<1, MAXB, 0, stream>>>(bc, MAXB);
    k_hist<<<512, TPB, 0, stream>>>(dst, bc, e, nb);
    k_scan<<<1, MAXB, 0, stream>>>(bc, bbase, gcur, nb);
    k_fillbin<<<nblk, TPB, 0, stream>>>(src, dst, gcur, binned, e, nb);
    k_sort<<<nb, NB, 0, stream>>>(binned, bbase, bc, csr, rowptr, dinv, n, nb, e);
    k_g1<<<gn, TPB, 0, stream>>>(x, W1, dinv, g1, n);
    k_gat1<<<gw, TPB, 0, stream>>>(g1, csr, rowptr, dinv, b1, W2, g2, n);
    k_gat2<<<gw, TPB, 0, stream>>>(g2, csr, rowptr, dinv, b2, Wfc, bfc, out, n);
}